// Round 6
// baseline (256.342 us; speedup 1.0000x reference)
//
#include <hip/hip_runtime.h>
#include <hip/hip_bf16.h>
#include <math.h>

// Problem constants
#define BQ 128
#define PP 256
#define MQ 16
#define MP 32
#define DD 768
#define MROWS (BQ*MQ)   // 2048
#define NROWS (PP*MP)   // 8192

typedef __bf16 bf16x8 __attribute__((ext_vector_type(8)));
typedef float  f32x4  __attribute__((ext_vector_type(4)));

// ---------- fp32 -> bf16 RTNE ----------
__device__ inline ushort bf16r(float f) {
    unsigned u = __float_as_uint(f);
    return (ushort)((u + 0x7FFFu + ((u >> 16) & 1u)) >> 16);
}

__global__ void conv_bf16_v4(const float4* __restrict__ in, ushort4* __restrict__ out, int n4) {
    int idx = blockIdx.x * blockDim.x + threadIdx.x;
    if (idx < n4) {
        float4 x = in[idx];
        ushort4 o;
        o.x = bf16r(x.x); o.y = bf16r(x.y); o.z = bf16r(x.z); o.w = bf16r(x.w);
        out[idx] = o;
    }
}

// ---------- barrier-free LDS-free fused GEMM + selection ----------
// Block = 64x128 tile, 4 waves in 2x2; each wave owns a 32x64 quadrant and
// loads its MFMA fragments STRAIGHT from global (L1/L2-served; the 2x2 wave
// grid makes addresses pairwise identical -> L1 dedup). No __syncthreads
// anywhere: waves free-run, so selection VALU overlaps other waves' MFMA
// (m114 co-scheduling), and no vmcnt(0) barrier drains.
// Selection: single descending key set; bottom_l = total - top_{n-l}
// (complement trick) -> two independent threshold descents on one key array.

__device__ inline float key_to_float(unsigned kk) {
    return (kk & 0x80000000u) ? __uint_as_float(kk & 0x7FFFFFFFu)
                              : __uint_as_float(~kk);
}

__device__ inline float softplus_f(float x) {
    return (x > 20.f) ? x : log1pf(expf(x));
}

__global__ __launch_bounds__(256) void gemm_select(const ushort* __restrict__ A,
                                                   const ushort* __restrict__ B,
                                                   const int* __restrict__ qm,
                                                   const int* __restrict__ pm,
                                                   const float* __restrict__ araw,
                                                   const float* __restrict__ braw,
                                                   float* __restrict__ logits) {
    const int tid  = threadIdx.x;
    const int lane = tid & 63;
    const int wid  = tid >> 6;        // 4 waves, 2x2 over 64x128
    const int wr   = wid >> 1;        // row half
    const int wc   = wid & 1;         // col half
    const int tm = blockIdx.y * 64 + wr * 32;
    const int tn = blockIdx.x * 128 + wc * 64;
    const int bBase = blockIdx.y * 4;
    const int pBase = blockIdx.x * 4;

    // ---- per-wave mask words: 2 q-blocks, 2 p-blocks
    unsigned qw[2]; int nq[2];
    #pragma unroll
    for (int t = 0; t < 2; ++t) {
        bool v = (lane < MQ) && (qm[(bBase + wr * 2 + t) * MQ + lane] != 0);
        unsigned long long bal = __ballot(v);
        qw[t] = (unsigned)bal;
        nq[t] = __popcll(bal);
    }
    unsigned pw[2]; int np_[2];
    #pragma unroll
    for (int t = 0; t < 2; ++t) {
        bool v = (lane < MP) && (pm[(pBase + wc * 2 + t) * MP + lane] != 0);
        unsigned long long bal = __ballot(v);
        pw[t] = (unsigned)bal;
        np_[t] = __popcll(bal);
    }

    // ---- GEMM phase: fragments direct from global
    f32x4 acc[2][4];
    #pragma unroll
    for (int i = 0; i < 2; ++i)
        #pragma unroll
        for (int j = 0; j < 4; ++j) {
            f32x4 z = {0.f, 0.f, 0.f, 0.f};
            acc[i][j] = z;
        }

    const int r0 = lane & 15;
    const int q  = lane >> 4;

    // per-fragment base pointers (k advances via immediate offsets)
    const ushort* pa0 = A + (size_t)(tm + r0) * DD + q * 8;
    const ushort* pa1 = pa0 + 16 * DD;
    const ushort* pb0 = B + (size_t)(tn + r0) * DD + q * 8;
    const ushort* pb1 = pb0 + 16 * DD;
    const ushort* pb2 = pb0 + 32 * DD;
    const ushort* pb3 = pb0 + 48 * DD;

    #pragma unroll 6
    for (int k0 = 0; k0 < DD; k0 += 32) {
        bf16x8 af0 = *(const bf16x8*)(pa0 + k0);
        bf16x8 af1 = *(const bf16x8*)(pa1 + k0);
        bf16x8 bf0 = *(const bf16x8*)(pb0 + k0);
        bf16x8 bf1 = *(const bf16x8*)(pb1 + k0);
        bf16x8 bf2 = *(const bf16x8*)(pb2 + k0);
        bf16x8 bf3 = *(const bf16x8*)(pb3 + k0);

        acc[0][0] = __builtin_amdgcn_mfma_f32_16x16x32_bf16(af0, bf0, acc[0][0], 0, 0, 0);
        acc[0][1] = __builtin_amdgcn_mfma_f32_16x16x32_bf16(af0, bf1, acc[0][1], 0, 0, 0);
        acc[0][2] = __builtin_amdgcn_mfma_f32_16x16x32_bf16(af0, bf2, acc[0][2], 0, 0, 0);
        acc[0][3] = __builtin_amdgcn_mfma_f32_16x16x32_bf16(af0, bf3, acc[0][3], 0, 0, 0);
        acc[1][0] = __builtin_amdgcn_mfma_f32_16x16x32_bf16(af1, bf0, acc[1][0], 0, 0, 0);
        acc[1][1] = __builtin_amdgcn_mfma_f32_16x16x32_bf16(af1, bf1, acc[1][1], 0, 0, 0);
        acc[1][2] = __builtin_amdgcn_mfma_f32_16x16x32_bf16(af1, bf2, acc[1][2], 0, 0, 0);
        acc[1][3] = __builtin_amdgcn_mfma_f32_16x16x32_bf16(af1, bf3, acc[1][3], 0, 0, 0);
    }

    // ---- selection phase: 4 pairs per wave, straight from acc registers
    // C/D layout (m89): row=(lane>>4)*4+(t&3), col=(t>>2)*16+(lane&15)
    float aco = softplus_f(araw[0]);
    float bco = softplus_f(braw[0]);
    const int rowb = (lane >> 4) * 4;
    const int colb = lane & 15;

    #pragma unroll 1
    for (int pair = 0; pair < 4; ++pair) {
        f32x4 w0, w1; unsigned qwv, pwv; int nqv, npv;
        switch (pair) {
        case 0:  w0 = acc[0][0]; w1 = acc[0][1]; qwv = qw[0]; nqv = nq[0]; pwv = pw[0]; npv = np_[0]; break;
        case 1:  w0 = acc[0][2]; w1 = acc[0][3]; qwv = qw[0]; nqv = nq[0]; pwv = pw[1]; npv = np_[1]; break;
        case 2:  w0 = acc[1][0]; w1 = acc[1][1]; qwv = qw[1]; nqv = nq[1]; pwv = pw[0]; npv = np_[0]; break;
        default: w0 = acc[1][2]; w1 = acc[1][3]; qwv = qw[1]; nqv = nq[1]; pwv = pw[1]; npv = np_[1]; break;
        }

        int n  = nqv * npv;               // >= 1
        int k  = (4 * n) / 10; if (k < 1) k = 1;
        int m2 = n - (8 * n) / 10;        // complement count, >= 1

        float v[8] = {w0[0], w0[1], w0[2], w0[3], w1[0], w1[1], w1[2], w1[3]};
        unsigned key[8];
        float tot = 0.f;
        #pragma unroll
        for (int t = 0; t < 8; ++t) {
            int row = rowb + (t & 3);
            int col = (t >> 2) * 16 + colb;
            unsigned uu = __float_as_uint(v[t]);
            unsigned kk = (uu & 0x80000000u) ? ~uu : (uu | 0x80000000u);
            bool val = (((qwv >> row) & 1u) != 0u) && (((pwv >> col) & 1u) != 0u);
            key[t] = val ? (kk >> 16) : 0u;   // valid keys >= 1
            if (val) tot += v[t];
        }

        // dual MSB-first radix descent on one key set (2 independent chains)
        unsigned T1 = 0u, T2 = 0u;
        for (int bit = 15; bit >= 0; --bit) {
            unsigned c1 = T1 | (1u << bit);
            unsigned c2 = T2 | (1u << bit);
            int cnt1 = 0, cnt2 = 0;
            #pragma unroll
            for (int t = 0; t < 8; ++t) {
                cnt1 += __popcll(__ballot(key[t] >= c1));
                cnt2 += __popcll(__ballot(key[t] >= c2));
            }
            if (cnt1 >= k)  T1 = c1;
            if (cnt2 >= m2) T2 = c2;
        }

        // tie-corrected sums
        float S1 = 0.f, S2 = 0.f;
        int c1n = 0, c2n = 0;
        #pragma unroll
        for (int t = 0; t < 8; ++t) {
            if (key[t] > T1) S1 += v[t];
            if (key[t] > T2) S2 += v[t];
            c1n += __popcll(__ballot(key[t] > T1));
            c2n += __popcll(__ballot(key[t] > T2));
        }
        #pragma unroll
        for (int off = 32; off > 0; off >>= 1) {
            S1  += __shfl_xor(S1,  off, 64);
            S2  += __shfl_xor(S2,  off, 64);
            tot += __shfl_xor(tot, off, 64);
        }

        float f1 = key_to_float(T1 << 16);
        float f2 = key_to_float(T2 << 16);
        float top   = S1 + (float)(k  - c1n) * f1;
        float topm2 = S2 + (float)(m2 - c2n) * f2;
        float bot   = tot - topm2;

        if (lane == 0) {
            int bl = pair >> 1, pl = pair & 1;
            logits[(bBase + wr * 2 + bl) * PP + (pBase + wc * 2 + pl)] = aco * top - bco * bot;
        }
    }
}

// ---------- loss = mean_b (lse(logits[b,:]) - logits[b,b]) ----------
__global__ __launch_bounds__(256) void loss_kernel(const float* __restrict__ logits,
                                                   float* __restrict__ loss_out) {
    __shared__ float warr[4];
    const int lane = threadIdx.x & 63;
    const int wid  = threadIdx.x >> 6;
    float acc = 0.f;
    for (int r = wid; r < BQ; r += 4) {
        const float* row = logits + r * PP;
        float x0 = row[lane], x1 = row[lane + 64], x2 = row[lane + 128], x3 = row[lane + 192];
        float m = fmaxf(fmaxf(x0, x1), fmaxf(x2, x3));
        #pragma unroll
        for (int off = 32; off > 0; off >>= 1)
            m = fmaxf(m, __shfl_xor(m, off, 64));
        float s = expf(x0 - m) + expf(x1 - m) + expf(x2 - m) + expf(x3 - m);
        #pragma unroll
        for (int off = 32; off > 0; off >>= 1)
            s += __shfl_xor(s, off, 64);
        float lse = m + logf(s);
        float diag = row[r];
        acc += (lse - diag);
    }
    if (lane == 0) warr[wid] = acc;
    __syncthreads();
    if (threadIdx.x == 0)
        loss_out[0] = (warr[0] + warr[1] + warr[2] + warr[3]) / (float)BQ;
}

extern "C" void kernel_launch(void* const* d_in, const int* in_sizes, int n_in,
                              void* d_out, int out_size, void* d_ws, size_t ws_size,
                              hipStream_t stream) {
    const float* q  = (const float*)d_in[0];
    const float* pe = (const float*)d_in[1];
    const int*   qm = (const int*)d_in[2];
    const int*   pm = (const int*)d_in[3];
    const float* ar = (const float*)d_in[4];
    const float* br = (const float*)d_in[5];
    float* out = (float*)d_out;           // [0] = loss, [1..32768] = logits

    // workspace: qb | pb (bf16 copies)
    char* ws = (char*)d_ws;
    ushort* qb  = (ushort*)ws;
    ushort* pb  = (ushort*)(ws + (size_t)MROWS * DD * 2);

    // 1) convert fp32 -> bf16
    int nq4 = MROWS * DD / 4;
    int np4 = NROWS * DD / 4;
    conv_bf16_v4<<<(nq4 + 255) / 256, 256, 0, stream>>>((const float4*)q,  (ushort4*)qb, nq4);
    conv_bf16_v4<<<(np4 + 255) / 256, 256, 0, stream>>>((const float4*)pe, (ushort4*)pb, np4);

    // 2) fused barrier-free sim-GEMM + dual top-k -> logits
    dim3 gg(NROWS / 128, MROWS / 64, 1);   // (64, 32) = 2048 blocks
    gemm_select<<<gg, 256, 0, stream>>>(qb, pb, qm, pm, ar, br, out + 1);

    // 3) loss
    loss_kernel<<<1, 256, 0, stream>>>(out + 1, out);
}

// Round 7
// 202.452 us; speedup vs baseline: 1.2662x; 1.2662x over previous
//
#include <hip/hip_runtime.h>
#include <hip/hip_bf16.h>
#include <math.h>

// Problem constants
#define BQ 128
#define PP 256
#define MQ 16
#define MP 32
#define DD 768
#define MROWS (BQ*MQ)   // 2048
#define NROWS (PP*MP)   // 8192

typedef __bf16 bf16x8 __attribute__((ext_vector_type(8)));
typedef float  f32x4  __attribute__((ext_vector_type(4)));

// ---------- fp32 -> bf16 RTNE ----------
__device__ inline ushort bf16r(float f) {
    unsigned u = __float_as_uint(f);
    return (ushort)((u + 0x7FFFu + ((u >> 16) & 1u)) >> 16);
}

__global__ void conv_bf16_v4(const float4* __restrict__ in, ushort4* __restrict__ out, int n4) {
    int idx = blockIdx.x * blockDim.x + threadIdx.x;
    if (idx < n4) {
        float4 x = in[idx];
        ushort4 o;
        o.x = bf16r(x.x); o.y = bf16r(x.y); o.z = bf16r(x.z); o.w = bf16r(x.w);
        out[idx] = o;
    }
}

// ---------- fused GEMM (128x128, BK=64) + register-resident selection ----------
// BK=64 halves barrier count vs R4/R5 (12 K-iters). LDS rows are 128 B =
// 8 x 16B slots; slot swizzle phys = logical ^ (row & 7) keeps global_load_lds
// lane-contiguous AND makes 16-row fragment reads 2-way bank aliased (free).
// Selection: 8 pairs/wave from acc regs, processed as 4 groups of 2 pairs
// interleaved (4 independent radix chains hide scalar-dependency latency).
#define BK 64
#define LDSU 64    // ushorts per row (128 B)

__device__ inline void load16_to_lds(const ushort* g, ushort* l) {
    __builtin_amdgcn_global_load_lds(
        (const __attribute__((address_space(1))) unsigned int*)(g),
        (__attribute__((address_space(3))) unsigned int*)(l),
        16, 0, 0);
}

__device__ inline float key_to_float(unsigned kk) {
    return (kk & 0x80000000u) ? __uint_as_float(kk & 0x7FFFFFFFu)
                              : __uint_as_float(~kk);
}

__device__ inline float softplus_f(float x) {
    return (x > 20.f) ? x : log1pf(expf(x));
}

__global__ __launch_bounds__(256) void gemm_select(const ushort* __restrict__ A,
                                                   const ushort* __restrict__ B,
                                                   const int* __restrict__ qm,
                                                   const int* __restrict__ pm,
                                                   const float* __restrict__ araw,
                                                   const float* __restrict__ braw,
                                                   float* __restrict__ logits) {
    __shared__ ushort sA[128 * LDSU];   // 16 KB
    __shared__ ushort sB[128 * LDSU];   // 16 KB

    const int tid  = threadIdx.x;
    const int lane = tid & 63;
    const int wid  = tid >> 6;        // 4 waves, 2x2 over 128x128
    const int wr   = wid >> 1;
    const int wc   = wid & 1;
    const int tileM = blockIdx.y * 128;
    const int tileN = blockIdx.x * 128;
    const int bBase = blockIdx.y * 8;
    const int pBase = blockIdx.x * 4;

    // ---- per-wave mask words: 4 q-blocks (row half), 2 p-blocks (col half)
    unsigned qw[4]; int nq[4];
    #pragma unroll
    for (int t = 0; t < 4; ++t) {
        bool v = (lane < MQ) && (qm[(bBase + wr * 4 + t) * MQ + lane] != 0);
        unsigned long long bal = __ballot(v);
        qw[t] = (unsigned)bal;
        nq[t] = __popcll(bal);
    }
    unsigned pw[2]; int np_[2];
    #pragma unroll
    for (int t = 0; t < 2; ++t) {
        bool v = (lane < MP) && (pm[(pBase + wc * 2 + t) * MP + lane] != 0);
        unsigned long long bal = __ballot(v);
        pw[t] = (unsigned)bal;
        np_[t] = __popcll(bal);
    }

    // ---- GEMM phase
    f32x4 acc[4][4];
    #pragma unroll
    for (int i = 0; i < 4; ++i)
        #pragma unroll
        for (int j = 0; j < 4; ++j) {
            f32x4 z = {0.f, 0.f, 0.f, 0.f};
            acc[i][j] = z;
        }

    // staging: one wave-load = 8 rows x 128B. lane -> row=lane>>3, slot=lane&7,
    // global logical chunk = slot ^ row (swizzle key = abs row & 7).
    const int slr  = lane >> 3;                          // row within 8-row chunk
    const int slog = ((lane & 7) ^ slr) << 3;            // logical ushort k-offset
    // fragment reads
    const int r0 = lane & 15;
    const int q  = lane >> 4;

    for (int k0 = 0; k0 < DD; k0 += BK) {
        // A: 16 chunks of 8 rows; wave w does chunks 4w..4w+3. Same for B.
        #pragma unroll
        for (int c = 0; c < 4; ++c) {
            int chunk = wid * 4 + c;
            int row   = chunk * 8 + slr;
            load16_to_lds(A + (size_t)(tileM + row) * DD + k0 + slog, &sA[chunk * 8 * LDSU]);
            load16_to_lds(B + (size_t)(tileN + row) * DD + k0 + slog, &sB[chunk * 8 * LDSU]);
        }
        __syncthreads();

        #pragma unroll
        for (int ks = 0; ks < 2; ++ks) {
            bf16x8 af[4], bfr[4];
            #pragma unroll
            for (int mi = 0; mi < 4; ++mi) {
                int row  = wr * 64 + mi * 16 + r0;
                int phys = (ks * 4 + q) ^ (r0 & 7);
                af[mi] = *(const bf16x8*)(&sA[row * LDSU + phys * 8]);
            }
            #pragma unroll
            for (int ni = 0; ni < 4; ++ni) {
                int row  = wc * 64 + ni * 16 + r0;
                int phys = (ks * 4 + q) ^ (r0 & 7);
                bfr[ni] = *(const bf16x8*)(&sB[row * LDSU + phys * 8]);
            }
            #pragma unroll
            for (int mi = 0; mi < 4; ++mi)
                #pragma unroll
                for (int ni = 0; ni < 4; ++ni)
                    acc[mi][ni] = __builtin_amdgcn_mfma_f32_16x16x32_bf16(af[mi], bfr[ni], acc[mi][ni], 0, 0, 0);
        }
        __syncthreads();
    }

    // ---- selection: 8 pairs/wave, 4 groups x 2 interleaved pairs
    // C/D layout (m89): row=(lane>>4)*4+(t&3), col=(t>>2)*16+(lane&15)
    float aco = softplus_f(araw[0]);
    float bco = softplus_f(braw[0]);
    const int rowb = (lane >> 4) * 4;
    const int colb = lane & 15;

    #pragma unroll 1
    for (int g = 0; g < 4; ++g) {
        f32x4 a0, a1, b0, b1; unsigned qwv; int nqv;
        switch (g) {
        case 0:  a0 = acc[0][0]; a1 = acc[0][1]; b0 = acc[0][2]; b1 = acc[0][3]; qwv = qw[0]; nqv = nq[0]; break;
        case 1:  a0 = acc[1][0]; a1 = acc[1][1]; b0 = acc[1][2]; b1 = acc[1][3]; qwv = qw[1]; nqv = nq[1]; break;
        case 2:  a0 = acc[2][0]; a1 = acc[2][1]; b0 = acc[2][2]; b1 = acc[2][3]; qwv = qw[2]; nqv = nq[2]; break;
        default: a0 = acc[3][0]; a1 = acc[3][1]; b0 = acc[3][2]; b1 = acc[3][3]; qwv = qw[3]; nqv = nq[3]; break;
        }

        int nA  = nqv * np_[0];
        int kA  = (4 * nA) / 10; if (kA < 1) kA = 1;
        int mA  = nA - (8 * nA) / 10;
        int nB  = nqv * np_[1];
        int kB  = (4 * nB) / 10; if (kB < 1) kB = 1;
        int mB  = nB - (8 * nB) / 10;

        float vA[8] = {a0[0], a0[1], a0[2], a0[3], a1[0], a1[1], a1[2], a1[3]};
        float vB[8] = {b0[0], b0[1], b0[2], b0[3], b1[0], b1[1], b1[2], b1[3]};
        unsigned keyA[8], keyB[8];
        float totA = 0.f, totB = 0.f;
        #pragma unroll
        for (int t = 0; t < 8; ++t) {
            int row = rowb + (t & 3);
            int col = (t >> 2) * 16 + colb;
            bool qv = ((qwv >> row) & 1u) != 0u;
            unsigned ua = __float_as_uint(vA[t]);
            unsigned ka = (ua & 0x80000000u) ? ~ua : (ua | 0x80000000u);
            bool valA = qv && (((pw[0] >> col) & 1u) != 0u);
            keyA[t] = valA ? (ka >> 16) : 0u;
            if (valA) totA += vA[t];
            unsigned ub = __float_as_uint(vB[t]);
            unsigned kb = (ub & 0x80000000u) ? ~ub : (ub | 0x80000000u);
            bool valB = qv && (((pw[1] >> col) & 1u) != 0u);
            keyB[t] = valB ? (kb >> 16) : 0u;
            if (valB) totB += vB[t];
        }

        // 4 interleaved MSB-first radix chains (topA, botA', topB, botB')
        unsigned T1A = 0u, T2A = 0u, T1B = 0u, T2B = 0u;
        for (int bit = 15; bit >= 0; --bit) {
            unsigned msk = 1u << bit;
            unsigned c1A = T1A | msk, c2A = T2A | msk;
            unsigned c1B = T1B | msk, c2B = T2B | msk;
            int n1A = 0, n2A = 0, n1B = 0, n2B = 0;
            #pragma unroll
            for (int t = 0; t < 8; ++t) {
                n1A += __popcll(__ballot(keyA[t] >= c1A));
                n2A += __popcll(__ballot(keyA[t] >= c2A));
                n1B += __popcll(__ballot(keyB[t] >= c1B));
                n2B += __popcll(__ballot(keyB[t] >= c2B));
            }
            if (n1A >= kA) T1A = c1A;
            if (n2A >= mA) T2A = c2A;
            if (n1B >= kB) T1B = c1B;
            if (n2B >= mB) T2B = c2B;
        }

        // tie-corrected sums
        float S1A = 0.f, S2A = 0.f, S1B = 0.f, S2B = 0.f;
        int c1An = 0, c2An = 0, c1Bn = 0, c2Bn = 0;
        #pragma unroll
        for (int t = 0; t < 8; ++t) {
            if (keyA[t] > T1A) S1A += vA[t];
            if (keyA[t] > T2A) S2A += vA[t];
            if (keyB[t] > T1B) S1B += vB[t];
            if (keyB[t] > T2B) S2B += vB[t];
            c1An += __popcll(__ballot(keyA[t] > T1A));
            c2An += __popcll(__ballot(keyA[t] > T2A));
            c1Bn += __popcll(__ballot(keyB[t] > T1B));
            c2Bn += __popcll(__ballot(keyB[t] > T2B));
        }
        #pragma unroll
        for (int off = 32; off > 0; off >>= 1) {
            S1A += __shfl_xor(S1A, off, 64);
            S2A += __shfl_xor(S2A, off, 64);
            S1B += __shfl_xor(S1B, off, 64);
            S2B += __shfl_xor(S2B, off, 64);
            totA += __shfl_xor(totA, off, 64);
            totB += __shfl_xor(totB, off, 64);
        }

        if (lane == 0) {
            float topA = S1A + (float)(kA - c1An) * key_to_float(T1A << 16);
            float cmpA = S2A + (float)(mA - c2An) * key_to_float(T2A << 16);
            float botA = totA - cmpA;
            float topB = S1B + (float)(kB - c1Bn) * key_to_float(T1B << 16);
            float cmpB = S2B + (float)(mB - c2Bn) * key_to_float(T2B << 16);
            float botB = totB - cmpB;
            int lrow = (bBase + wr * 4 + g) * PP + pBase + wc * 2;
            logits[lrow]     = aco * topA - bco * botA;
            logits[lrow + 1] = aco * topB - bco * botB;
        }
    }
}

// ---------- loss = mean_b (lse(logits[b,:]) - logits[b,b]) ----------
__global__ __launch_bounds__(256) void loss_kernel(const float* __restrict__ logits,
                                                   float* __restrict__ loss_out) {
    __shared__ float warr[4];
    const int lane = threadIdx.x & 63;
    const int wid  = threadIdx.x >> 6;
    float acc = 0.f;
    for (int r = wid; r < BQ; r += 4) {
        const float* row = logits + r * PP;
        float x0 = row[lane], x1 = row[lane + 64], x2 = row[lane + 128], x3 = row[lane + 192];
        float m = fmaxf(fmaxf(x0, x1), fmaxf(x2, x3));
        #pragma unroll
        for (int off = 32; off > 0; off >>= 1)
            m = fmaxf(m, __shfl_xor(m, off, 64));
        float s = expf(x0 - m) + expf(x1 - m) + expf(x2 - m) + expf(x3 - m);
        #pragma unroll
        for (int off = 32; off > 0; off >>= 1)
            s += __shfl_xor(s, off, 64);
        float lse = m + logf(s);
        float diag = row[r];
        acc += (lse - diag);
    }
    if (lane == 0) warr[wid] = acc;
    __syncthreads();
    if (threadIdx.x == 0)
        loss_out[0] = (warr[0] + warr[1] + warr[2] + warr[3]) / (float)BQ;
}

extern "C" void kernel_launch(void* const* d_in, const int* in_sizes, int n_in,
                              void* d_out, int out_size, void* d_ws, size_t ws_size,
                              hipStream_t stream) {
    const float* q  = (const float*)d_in[0];
    const float* pe = (const float*)d_in[1];
    const int*   qm = (const int*)d_in[2];
    const int*   pm = (const int*)d_in[3];
    const float* ar = (const float*)d_in[4];
    const float* br = (const float*)d_in[5];
    float* out = (float*)d_out;           // [0] = loss, [1..32768] = logits

    // workspace: qb | pb (bf16 copies)
    char* ws = (char*)d_ws;
    ushort* qb  = (ushort*)ws;
    ushort* pb  = (ushort*)(ws + (size_t)MROWS * DD * 2);

    // 1) convert fp32 -> bf16
    int nq4 = MROWS * DD / 4;
    int np4 = NROWS * DD / 4;
    conv_bf16_v4<<<(nq4 + 255) / 256, 256, 0, stream>>>((const float4*)q,  (ushort4*)qb, nq4);
    conv_bf16_v4<<<(np4 + 255) / 256, 256, 0, stream>>>((const float4*)pe, (ushort4*)pb, np4);

    // 2) fused sim-GEMM + dual top-k -> logits
    dim3 gg(NROWS / 128, MROWS / 128, 1);   // (64, 16) = 1024 blocks = 4/CU
    gemm_select<<<gg, 256, 0, stream>>>(qb, pb, qm, pm, ar, br, out + 1);

    // 3) loss
    loss_kernel<<<1, 256, 0, stream>>>(out + 1, out);
}

// Round 8
// 194.195 us; speedup vs baseline: 1.3200x; 1.0425x over previous
//
#include <hip/hip_runtime.h>
#include <hip/hip_bf16.h>
#include <math.h>

// Problem constants
#define BQ 128
#define PP 256
#define MQ 16
#define MP 32
#define DD 768
#define MROWS (BQ*MQ)   // 2048
#define NROWS (PP*MP)   // 8192

typedef __bf16 bf16x8 __attribute__((ext_vector_type(8)));
typedef float  f32x4  __attribute__((ext_vector_type(4)));

// ---------- fp32 -> bf16 RTNE (both tensors in one launch) ----------
__device__ inline ushort bf16r(float f) {
    unsigned u = __float_as_uint(f);
    return (ushort)((u + 0x7FFFu + ((u >> 16) & 1u)) >> 16);
}

#define NQ4 (MROWS*DD/4)   // 393216
#define NP4 (NROWS*DD/4)   // 1572864

__global__ void conv_bf16_both(const float4* __restrict__ q, const float4* __restrict__ p,
                               ushort4* __restrict__ qb, ushort4* __restrict__ pb) {
    int idx = blockIdx.x * blockDim.x + threadIdx.x;
    const float4* in; ushort4* out; int i;
    if (idx < NQ4) { in = q; out = qb; i = idx; }
    else           { in = p; out = pb; i = idx - NQ4; }
    float4 x = in[i];
    ushort4 o;
    o.x = bf16r(x.x); o.y = bf16r(x.y); o.z = bf16r(x.z); o.w = bf16r(x.w);
    out[i] = o;
}

// ---------- fused GEMM (64x128 bf16 MFMA tile) + register-resident selection ----
// R5 GEMM skeleton (best measured: 86 us plateau). Selection reworked:
//  - counting via per-lane v_addc accumulation + ONE packed butterfly per bit
//    (both radix chains in low16/high16 of one u32) -> no s_bcnt1/s_add chains
//    on the CU-shared scalar unit (R7 analysis: ~30 us SALU serialization).
//  - 12-bit keys (sign+exp+3 mantissa): 12 serial iterations, tie-bucket error
//    ~1 bf16 ulp*16 near thresholds (~+-10..30 logit error, budget 215).
#define BM 64
#define BN 128
#define BK 32
#define LDSU 32    // ushorts per staging row (64 B, unpadded for global_load_lds)

__device__ inline void load16_to_lds(const ushort* g, ushort* l) {
    __builtin_amdgcn_global_load_lds(
        (const __attribute__((address_space(1))) unsigned int*)(g),
        (__attribute__((address_space(3))) unsigned int*)(l),
        16, 0, 0);
}

__device__ inline float key_to_float(unsigned kk) {
    return (kk & 0x80000000u) ? __uint_as_float(kk & 0x7FFFFFFFu)
                              : __uint_as_float(~kk);
}

__device__ inline float softplus_f(float x) {
    return (x > 20.f) ? x : log1pf(expf(x));
}

__global__ __launch_bounds__(256) void gemm_select(const ushort* __restrict__ A,
                                                   const ushort* __restrict__ B,
                                                   const int* __restrict__ qm,
                                                   const int* __restrict__ pm,
                                                   const float* __restrict__ araw,
                                                   const float* __restrict__ braw,
                                                   float* __restrict__ logits) {
    __shared__ ushort sA[BM * LDSU];   // 4 KB
    __shared__ ushort sB[BN * LDSU];   // 8 KB

    const int tid  = threadIdx.x;
    const int lane = tid & 63;
    const int wid  = tid >> 6;        // 4 waves, 2x2 over 64x128
    const int wr   = wid >> 1;
    const int wc   = wid & 1;
    const int tileM = blockIdx.y * BM;
    const int tileN = blockIdx.x * BN;
    const int bBase = blockIdx.y * 4;
    const int pBase = blockIdx.x * 4;

    // ---- per-wave mask words: 2 q-blocks, 2 p-blocks
    unsigned qw[2]; int nq[2];
    #pragma unroll
    for (int t = 0; t < 2; ++t) {
        bool v = (lane < MQ) && (qm[(bBase + wr * 2 + t) * MQ + lane] != 0);
        unsigned long long bal = __ballot(v);
        qw[t] = (unsigned)bal;
        nq[t] = __popcll(bal);
    }
    unsigned pw[2]; int np_[2];
    #pragma unroll
    for (int t = 0; t < 2; ++t) {
        bool v = (lane < MP) && (pm[(pBase + wc * 2 + t) * MP + lane] != 0);
        unsigned long long bal = __ballot(v);
        pw[t] = (unsigned)bal;
        np_[t] = __popcll(bal);
    }

    // ---- GEMM phase (R5 verbatim)
    f32x4 acc[2][4];
    #pragma unroll
    for (int i = 0; i < 2; ++i)
        #pragma unroll
        for (int j = 0; j < 4; ++j) {
            f32x4 z = {0.f, 0.f, 0.f, 0.f};
            acc[i][j] = z;
        }

    const int lr  = lane >> 2;
    const int kcu = ((lane & 3) ^ ((lane >> 3) & 3)) << 3;
    const int r0    = lane & 15;
    const int q     = lane >> 4;
    const int physq = q ^ ((r0 >> 1) & 3);

    for (int k0 = 0; k0 < DD; k0 += BK) {
        {
            int rowA = wid * 16 + lr;
            load16_to_lds(A + (size_t)(tileM + rowA) * DD + k0 + kcu, &sA[wid * 16 * LDSU]);
            #pragma unroll
            for (int c = 0; c < 2; ++c) {
                int chunk = wid * 2 + c;
                int rowB  = chunk * 16 + lr;
                load16_to_lds(B + (size_t)(tileN + rowB) * DD + k0 + kcu, &sB[chunk * 16 * LDSU]);
            }
        }
        __syncthreads();

        bf16x8 af[2], bfr[4];
        #pragma unroll
        for (int mi = 0; mi < 2; ++mi)
            af[mi] = *(const bf16x8*)(&sA[(wr * 32 + mi * 16 + r0) * LDSU + physq * 8]);
        #pragma unroll
        for (int ni = 0; ni < 4; ++ni)
            bfr[ni] = *(const bf16x8*)(&sB[(wc * 64 + ni * 16 + r0) * LDSU + physq * 8]);

        #pragma unroll
        for (int mi = 0; mi < 2; ++mi)
            #pragma unroll
            for (int ni = 0; ni < 4; ++ni)
                acc[mi][ni] = __builtin_amdgcn_mfma_f32_16x16x32_bf16(af[mi], bfr[ni], acc[mi][ni], 0, 0, 0);
        __syncthreads();
    }

    // ---- selection: 4 pairs/wave from acc regs
    // C/D layout (m89): row=(lane>>4)*4+(t&3), col=(t>>2)*16+(lane&15)
    float aco = softplus_f(araw[0]);
    float bco = softplus_f(braw[0]);
    const int rowb = (lane >> 4) * 4;
    const int colb = lane & 15;

    #pragma unroll 1
    for (int pair = 0; pair < 4; ++pair) {
        f32x4 w0, w1; unsigned qwv, pwv; int nqv, npv;
        switch (pair) {
        case 0:  w0 = acc[0][0]; w1 = acc[0][1]; qwv = qw[0]; nqv = nq[0]; pwv = pw[0]; npv = np_[0]; break;
        case 1:  w0 = acc[0][2]; w1 = acc[0][3]; qwv = qw[0]; nqv = nq[0]; pwv = pw[1]; npv = np_[1]; break;
        case 2:  w0 = acc[1][0]; w1 = acc[1][1]; qwv = qw[1]; nqv = nq[1]; pwv = pw[0]; npv = np_[0]; break;
        default: w0 = acc[1][2]; w1 = acc[1][3]; qwv = qw[1]; nqv = nq[1]; pwv = pw[1]; npv = np_[1]; break;
        }

        int n  = nqv * npv;               // >= 1
        int k  = (4 * n) / 10; if (k < 1) k = 1;
        int m2 = n - (8 * n) / 10;        // complement rank, >= 1

        float v[8] = {w0[0], w0[1], w0[2], w0[3], w1[0], w1[1], w1[2], w1[3]};
        unsigned key[8];
        float tot = 0.f;
        #pragma unroll
        for (int t = 0; t < 8; ++t) {
            int row = rowb + (t & 3);
            int col = (t >> 2) * 16 + colb;
            unsigned uu = __float_as_uint(v[t]);
            unsigned kk = (uu & 0x80000000u) ? ~uu : (uu | 0x80000000u);
            bool val = (((qwv >> row) & 1u) != 0u) && (((pwv >> col) & 1u) != 0u);
            key[t] = val ? (kk >> 20) : 0u;   // 12-bit keys; valid >= 1
            if (val) tot += v[t];
        }

        // dual 12-bit MSB-first radix descent; per-lane VALU counting +
        // one packed butterfly per bit (low16 = top-k chain, high16 = compl.)
        unsigned T1 = 0u, T2 = 0u;
        for (int bit = 11; bit >= 0; --bit) {
            unsigned c1 = T1 | (1u << bit);
            unsigned c2 = T2 | (1u << bit);
            int cnt1 = 0, cnt2 = 0;
            #pragma unroll
            for (int t = 0; t < 8; ++t) {
                cnt1 += (key[t] >= c1) ? 1 : 0;
                cnt2 += (key[t] >= c2) ? 1 : 0;
            }
            int pk = cnt1 | (cnt2 << 16);
            #pragma unroll
            for (int off = 32; off > 0; off >>= 1)
                pk += __shfl_xor(pk, off, 64);
            if ((pk & 0xFFFF) >= k)  T1 = c1;
            if ((pk >> 16)    >= m2) T2 = c2;
        }

        // tie-corrected sums (counts packed-butterflied too; floats separate)
        float S1 = 0.f, S2 = 0.f;
        int c1n = 0, c2n = 0;
        #pragma unroll
        for (int t = 0; t < 8; ++t) {
            if (key[t] > T1) { S1 += v[t]; c1n += 1; }
            if (key[t] > T2) { S2 += v[t]; c2n += 1; }
        }
        int pc = c1n | (c2n << 16);
        #pragma unroll
        for (int off = 32; off > 0; off >>= 1) {
            S1  += __shfl_xor(S1,  off, 64);
            S2  += __shfl_xor(S2,  off, 64);
            tot += __shfl_xor(tot, off, 64);
            pc  += __shfl_xor(pc,  off, 64);
        }
        c1n = pc & 0xFFFF; c2n = pc >> 16;

        float f1 = key_to_float(T1 << 20);
        float f2 = key_to_float(T2 << 20);
        float top = S1 + (float)(k  - c1n) * f1;
        float cmp = S2 + (float)(m2 - c2n) * f2;
        float bot = tot - cmp;

        if (lane == 0) {
            int bl = pair >> 1, pl = pair & 1;
            logits[(bBase + wr * 2 + bl) * PP + (pBase + wc * 2 + pl)] = aco * top - bco * bot;
        }
    }
}

// ---------- loss = mean_b (lse(logits[b,:]) - logits[b,b]) ----------
__global__ __launch_bounds__(256) void loss_kernel(const float* __restrict__ logits,
                                                   float* __restrict__ loss_out) {
    __shared__ float warr[4];
    const int lane = threadIdx.x & 63;
    const int wid  = threadIdx.x >> 6;
    float acc = 0.f;
    for (int r = wid; r < BQ; r += 4) {
        const float* row = logits + r * PP;
        float x0 = row[lane], x1 = row[lane + 64], x2 = row[lane + 128], x3 = row[lane + 192];
        float m = fmaxf(fmaxf(x0, x1), fmaxf(x2, x3));
        #pragma unroll
        for (int off = 32; off > 0; off >>= 1)
            m = fmaxf(m, __shfl_xor(m, off, 64));
        float s = expf(x0 - m) + expf(x1 - m) + expf(x2 - m) + expf(x3 - m);
        #pragma unroll
        for (int off = 32; off > 0; off >>= 1)
            s += __shfl_xor(s, off, 64);
        float lse = m + logf(s);
        float diag = row[r];
        acc += (lse - diag);
    }
    if (lane == 0) warr[wid] = acc;
    __syncthreads();
    if (threadIdx.x == 0)
        loss_out[0] = (warr[0] + warr[1] + warr[2] + warr[3]) / (float)BQ;
}

extern "C" void kernel_launch(void* const* d_in, const int* in_sizes, int n_in,
                              void* d_out, int out_size, void* d_ws, size_t ws_size,
                              hipStream_t stream) {
    const float* q  = (const float*)d_in[0];
    const float* pe = (const float*)d_in[1];
    const int*   qm = (const int*)d_in[2];
    const int*   pm = (const int*)d_in[3];
    const float* ar = (const float*)d_in[4];
    const float* br = (const float*)d_in[5];
    float* out = (float*)d_out;           // [0] = loss, [1..32768] = logits

    // workspace: qb | pb (bf16 copies)
    char* ws = (char*)d_ws;
    ushort* qb  = (ushort*)ws;
    ushort* pb  = (ushort*)(ws + (size_t)MROWS * DD * 2);

    // 1) convert fp32 -> bf16 (single launch for both tensors)
    conv_bf16_both<<<(NQ4 + NP4) / 256, 256, 0, stream>>>(
        (const float4*)q, (const float4*)pe, (ushort4*)qb, (ushort4*)pb);

    // 2) fused sim-GEMM + dual top-k -> logits
    dim3 gg(NROWS / BN, MROWS / BM, 1);   // (64, 32) = 2048 blocks = 8/CU
    gemm_select<<<gg, 256, 0, stream>>>(qb, pb, qm, pm, ar, br, out + 1);

    // 3) loss
    loss_kernel<<<1, 256, 0, stream>>>(out + 1, out);
}